// Round 2
// baseline (150.303 us; speedup 1.0000x reference)
//
#include <hip/hip_runtime.h>
#include <math.h>

// Problem geometry (fixed by the reference): probability [64, 2, 512, 512] fp32.
constexpr int B       = 64;
constexpr int HW      = 512 * 512;        // pixels per (batch, channel)
constexpr int CHUNKS  = 32;               // blocks per batch -> 2048 blocks total
constexpr int PIX     = HW / CHUNKS;      // 8192 pixels per block
constexpr int THREADS = 256;
constexpr int NBLK    = B * CHUNKS;       // 2048

// d_ws layout: [0 .. NBLK) float partials | at byte 8192: u32 arrival counter.

__global__ __launch_bounds__(THREADS)
void lb_fused(const float* __restrict__ prob, float* __restrict__ partials,
              unsigned* __restrict__ counter, float* __restrict__ out) {
    const int blk = blockIdx.x;
    const int b   = blk >> 5;             // blk / CHUNKS
    const int c   = blk & (CHUNKS - 1);   // blk % CHUNKS

    const float4* __restrict__ x0 =
        reinterpret_cast<const float4*>(prob + (size_t)b * 2 * HW + (size_t)c * PIX);
    const float4* __restrict__ x1 =
        reinterpret_cast<const float4*>(prob + (size_t)b * 2 * HW + HW + (size_t)c * PIX);

    constexpr int N4 = PIX / 4;           // 2048 float4 per channel per block
    constexpr float LOG2E = 1.44269504088896341f;
    float acc = 0.f;
    #pragma unroll
    for (int it = 0; it < N4 / THREADS; ++it) {         // 8 iterations, fully unrolled
        const int i = it * THREADS + threadIdx.x;
        float4 a = x0[i];
        float4 d = x1[i];
        // sigmoid(d-a) = 1/(1+exp(a-d)); native exp2 + rcp (threshold is 312, plenty slack)
        acc += __builtin_amdgcn_rcpf(1.f + __expf((a.x - d.x)));
        acc += __builtin_amdgcn_rcpf(1.f + __expf((a.y - d.y)));
        acc += __builtin_amdgcn_rcpf(1.f + __expf((a.z - d.z)));
        acc += __builtin_amdgcn_rcpf(1.f + __expf((a.w - d.w)));
    }

    // wave64 reduction, then cross-wave via LDS
    #pragma unroll
    for (int off = 32; off > 0; off >>= 1)
        acc += __shfl_down(acc, off, 64);

    __shared__ float sdata[THREADS / 64];
    __shared__ bool  isLast;
    const int lane = threadIdx.x & 63;
    const int wid  = threadIdx.x >> 6;
    if (lane == 0) sdata[wid] = acc;
    __syncthreads();

    if (threadIdx.x == 0) {
        float s = 0.f;
        #pragma unroll
        for (int w = 0; w < THREADS / 64; ++w) s += sdata[w];
        partials[blk] = s;
        __threadfence();   // device-scope release: partial visible across XCDs
        unsigned old = __hip_atomic_fetch_add(counter, 1u, __ATOMIC_ACQ_REL,
                                              __HIP_MEMORY_SCOPE_AGENT);
        isLast = (old == (unsigned)(NBLK - 1));
    }
    __syncthreads();

    if (!isLast || threadIdx.x >= 64) return;

    // ---- final reduction: one wave, lane b = batch b ----
    __threadfence();       // acquire side
    const int lb = threadIdx.x;
    double s = 0.0;
    #pragma unroll
    for (int k = 0; k < CHUNKS; ++k) {
        float p = __hip_atomic_load(&partials[lb * CHUNKS + k],
                                    __ATOMIC_RELAXED, __HIP_MEMORY_SCOPE_AGENT);
        s += (double)p;
    }

    const double LOW  = 131050.0;
    const double HIGH = 131100.0;

    double dl  = s - LOW;
    double lvs = dl * dl;
    #pragma unroll
    for (int off = 32; off > 0; off >>= 1) lvs += __shfl_xor(lvs, off, 64);

    double contrib, count;
    if (s >= HIGH)      { double d = s - HIGH; contrib = d * d; count = 1.0; }
    else if (s <= LOW)  { contrib = lvs;                        count = (double)B; }
    else                { contrib = 0.0;                        count = 1.0; }

    double cs = contrib, cn = count;
    #pragma unroll
    for (int off = 32; off > 0; off >>= 1) {
        cs += __shfl_xor(cs, off, 64);
        cn += __shfl_xor(cn, off, 64);
    }
    if (lb == 0) out[0] = (float)(cs / cn);
}

extern "C" void kernel_launch(void* const* d_in, const int* in_sizes, int n_in,
                              void* d_out, int out_size, void* d_ws, size_t ws_size,
                              hipStream_t stream) {
    const float* prob     = (const float*)d_in[0];
    float*       out      = (float*)d_out;
    float*       partials = (float*)d_ws;
    unsigned*    counter  = (unsigned*)((char*)d_ws + NBLK * sizeof(float));

    // zero the arrival counter each call (graph-capturable async op)
    hipMemsetAsync(counter, 0, sizeof(unsigned), stream);
    lb_fused<<<NBLK, THREADS, 0, stream>>>(prob, partials, counter, out);
}

// Round 3
// 27.181 us; speedup vs baseline: 5.5297x; 5.5297x over previous
//
#include <hip/hip_runtime.h>
#include <math.h>

// Problem geometry (fixed by the reference): probability [64, 2, 512, 512] fp32.
constexpr int B       = 64;
constexpr int HW      = 512 * 512;        // pixels per (batch, channel)
constexpr int CHUNKS  = 32;               // blocks per batch -> 2048 blocks total
constexpr int PIX     = HW / CHUNKS;      // 8192 pixels per block
constexpr int THREADS = 256;
constexpr int NBLK    = B * CHUNKS;       // 2048
constexpr int ITER    = PIX / 4 / THREADS; // 8 float4 iterations per thread

// Kernel 1: per-block partial sums of sigmoid(x1 - x0) = softmax(axis=1)[ch 1].
// Load-first register staging: all 16 float4 loads in flight before compute.
__global__ __launch_bounds__(THREADS)
void lb_partials(const float* __restrict__ prob, float* __restrict__ partials) {
    const int blk = blockIdx.x;
    const int b   = blk >> 5;             // blk / CHUNKS
    const int c   = blk & (CHUNKS - 1);   // blk % CHUNKS

    const float4* __restrict__ x0 =
        reinterpret_cast<const float4*>(prob + (size_t)b * 2 * HW + (size_t)c * PIX);
    const float4* __restrict__ x1 =
        reinterpret_cast<const float4*>(prob + (size_t)b * 2 * HW + HW + (size_t)c * PIX);

    float4 a[ITER], d[ITER];
    #pragma unroll
    for (int it = 0; it < ITER; ++it) {
        const int i = it * THREADS + threadIdx.x;
        a[it] = x0[i];
        d[it] = x1[i];
    }

    float acc = 0.f;
    #pragma unroll
    for (int it = 0; it < ITER; ++it) {
        // sigmoid(d-a) = 1/(1+exp(a-d)); fast exp + rcp (abs threshold 312 — huge slack)
        acc += __builtin_amdgcn_rcpf(1.f + __expf(a[it].x - d[it].x));
        acc += __builtin_amdgcn_rcpf(1.f + __expf(a[it].y - d[it].y));
        acc += __builtin_amdgcn_rcpf(1.f + __expf(a[it].z - d[it].z));
        acc += __builtin_amdgcn_rcpf(1.f + __expf(a[it].w - d[it].w));
    }

    // wave64 reduction, then cross-wave via LDS
    #pragma unroll
    for (int off = 32; off > 0; off >>= 1)
        acc += __shfl_down(acc, off, 64);

    __shared__ float sdata[THREADS / 64];
    const int lane = threadIdx.x & 63;
    const int wid  = threadIdx.x >> 6;
    if (lane == 0) sdata[wid] = acc;
    __syncthreads();
    if (threadIdx.x == 0) {
        float s = 0.f;
        #pragma unroll
        for (int w = 0; w < THREADS / 64; ++w) s += sdata[w];
        partials[blk] = s;
    }
}

// Kernel 2: 256 threads. Thread t = (batch b = t>>2, quarter q = t&3) sums 8
// partials in double; 4-lane shuffle combine; wave 0 runs the scalar finale.
__global__ __launch_bounds__(256)
void lb_final(const float* __restrict__ partials, float* __restrict__ out) {
    __shared__ double s_sh[B];
    const int t = threadIdx.x;
    const int b = t >> 2;
    const int q = t & 3;

    double ps = 0.0;
    #pragma unroll
    for (int k = 0; k < 8; ++k)
        ps += (double)partials[b * CHUNKS + q * 8 + k];
    // combine the 4 lanes owning batch b (contiguous lanes within a wave)
    ps += __shfl_xor(ps, 1, 64);
    ps += __shfl_xor(ps, 2, 64);
    if (q == 0) s_sh[b] = ps;
    __syncthreads();

    if (t >= 64) return;
    const double s = s_sh[t];             // lane t = batch t

    const double LOW  = 131050.0;
    const double HIGH = 131100.0;

    // low_vec_sum = sum over the whole batch of (s - LOW)^2
    double dl  = s - LOW;
    double lvs = dl * dl;
    #pragma unroll
    for (int off = 32; off > 0; off >>= 1) lvs += __shfl_xor(lvs, off, 64);

    // Faithful reproduction of the reference's branchy contributions.
    double contrib, count;
    if (s >= HIGH)      { double dd = s - HIGH; contrib = dd * dd; count = 1.0; }
    else if (s <= LOW)  { contrib = lvs;                           count = (double)B; }
    else                { contrib = 0.0;                           count = 1.0; }

    double cs = contrib, cn = count;
    #pragma unroll
    for (int off = 32; off > 0; off >>= 1) {
        cs += __shfl_xor(cs, off, 64);
        cn += __shfl_xor(cn, off, 64);
    }
    if (t == 0) out[0] = (float)(cs / cn);
}

extern "C" void kernel_launch(void* const* d_in, const int* in_sizes, int n_in,
                              void* d_out, int out_size, void* d_ws, size_t ws_size,
                              hipStream_t stream) {
    const float* prob     = (const float*)d_in[0];
    float*       out      = (float*)d_out;
    float*       partials = (float*)d_ws;   // 2048 floats, written before read

    lb_partials<<<NBLK, THREADS, 0, stream>>>(prob, partials);
    lb_final<<<1, 256, 0, stream>>>(partials, out);
}